// Round 4
// baseline (3354.222 us; speedup 1.0000x reference)
//
#include <hip/hip_runtime.h>
#include <hip/hip_bf16.h>

// ---------------------------------------------------------------------------
// PredRNN (patched) — R4: gate-local wave tiles.
// kcellA: wave = 16co x 7 gates x 64px, K walks inputs {x(7 gates), h(4), m(3)};
//         B-frags shared across gates; epilogue thread-local (no slab exchange).
// kcellB: wave = 64co x 32px, convO(3x3,128ci) + convL(1x1) in one wave,
//         gate2 epilogue thread-local.
// Weight A-frags pre-packed in exact consumption order, global-direct (L2).
// ---------------------------------------------------------------------------

typedef __bf16 bf16x8 __attribute__((ext_vector_type(8)));
typedef float f32x4 __attribute__((ext_vector_type(4)));

namespace {
constexpr int  T     = 19;
constexpr int  INLEN = 10;

// workspace offsets (in floats)
constexpr long OFF_XPB   = 0;            // bf16 [80][1024][64]
constexpr long OFF_OUTSB = 2621440;      // bf16 [19][8][1024][64]
constexpr long OFF_HB    = 7602176;      // bf16 [4][8][1024][64]
constexpr long OFF_MB    = 8650752;      // bf16 2x [8][1024][64] (ping-pong)
constexpr long OFF_C     = 9175040;      // fp32 [4][8][64][1024]
constexpr long OFF_M     = 11272192;     // fp32 [8][64][1024]
constexpr long OFF_MEMB  = 11796480;     // bf16 [8][1024][128]
constexpr long OFF_OP    = 12320768;     // fp32 [8][64][1024]
constexpr long OFF_WFA   = 12845056;     // bf16 4 x 4 x 129024
constexpr long OFF_WFB   = 13877248;     // bf16 4 x 81920
constexpr long OFF_WFD   = 14041088;     // bf16 36864
constexpr long OFF_BA    = 14059520;     // fp32 4 x 448
constexpr long WS_NEEDED_FLOATS = 14061312;
}

__device__ __forceinline__ float sigf(float x)     { return 1.f / (1.f + __expf(-x)); }
__device__ __forceinline__ float tanhfast(float x) { return 2.f / (1.f + __expf(-2.f * x)) - 1.f; }
__device__ __forceinline__ unsigned short f2b(float f) {
  __hip_bfloat16 h = __float2bfloat16(f);
  return __builtin_bit_cast(unsigned short, h);
}
__device__ __forceinline__ f32x4 mfma16(bf16x8 a, bf16x8 b, f32x4 c) {
  return __builtin_amdgcn_mfma_f32_16x16x32_bf16(a, b, c, 0, 0, 0);
}

// stage one input's 4-row halo strip (64ci channels-last, swizzled 16B slots)
__device__ __forceinline__ void stage64(const unsigned short* __restrict__ bp,
                                        unsigned short* dst, int s, int by) {
  int slot = s >> 3, cg = s & 7;
  int rr = slot / 34, cl = slot - rr * 34;
  int gr = by * 2 - 1 + rr, gc = cl - 1;
  uint4 v = make_uint4(0u, 0u, 0u, 0u);
  if ((unsigned)gr < 32u && (unsigned)gc < 32u)
    v = *(const uint4*)(bp + ((long)(gr * 32 + gc) << 6) + cg * 8);
  *(uint4*)(dst + slot * 64 + ((cg ^ (slot & 7)) * 8)) = v;
}

// one K-section (one physical input, NG gates at acc slots S0..S0+NG-1).
// 2-row output tile: staged rows ridx=pf_row+dy, combos (pf_row,dy).
template<int NG, int S0, int FOFF>
__device__ __forceinline__ void conv_section(
    const unsigned short* sb, const unsigned short* wA,
    int lane, int q, int n16, f32x4 (&acc)[7][4])
{
  #pragma unroll
  for (int cc = 0; cc < 2; ++cc) {
    #pragma unroll
    for (int dx = 0; dx < 3; ++dx) {
      bf16x8 A[3][NG];
      #pragma unroll
      for (int dy = 0; dy < 3; ++dy)
        #pragma unroll
        for (int s = 0; s < NG; ++s)
          A[dy][s] = *(const bf16x8*)(wA +
              (long)(FOFF + (cc * 3 + dx) * (3 * NG) + dy * NG + s) * 512 + lane * 8);
      const int cs = cc * 4 + q;
      #pragma unroll
      for (int cg = 0; cg < 2; ++cg) {
        bf16x8 B[4];
        #pragma unroll
        for (int ridx = 0; ridx < 4; ++ridx) {
          const int slot = ridx * 34 + cg * 16 + dx + n16;
          B[ridx] = *(const bf16x8*)(sb + slot * 64 + ((cs ^ (slot & 7)) * 8));
        }
        #pragma unroll
        for (int s = 0; s < NG; ++s) {
          acc[S0 + s][cg]     = mfma16(A[0][s], B[0], acc[S0 + s][cg]);
          acc[S0 + s][cg]     = mfma16(A[1][s], B[1], acc[S0 + s][cg]);
          acc[S0 + s][cg]     = mfma16(A[2][s], B[2], acc[S0 + s][cg]);
          acc[S0 + s][2 + cg] = mfma16(A[0][s], B[1], acc[S0 + s][2 + cg]);
          acc[S0 + s][2 + cg] = mfma16(A[1][s], B[2], acc[S0 + s][2 + cg]);
          acc[S0 + s][2 + cg] = mfma16(A[2][s], B[3], acc[S0 + s][2 + cg]);
        }
      }
    }
  }
}

// ---------------------------------------------------------------------------
// kcellA: grid (8, 16 row-pairs, 2 co-halves), 128 threads (2 waves).
// Wave co-group g = z*2+w: covers co [g*16, g*16+16) of EVERY gate, 64 px.
// ---------------------------------------------------------------------------
__global__ __launch_bounds__(128) void kcellA(
    const unsigned short* __restrict__ in0, long in0bs,
    const unsigned short* __restrict__ hB,
    const unsigned short* __restrict__ mBr,
    const unsigned short* __restrict__ wfAl,
    const float* __restrict__ bAl,
    float* __restrict__ C, float* __restrict__ M,
    unsigned short* __restrict__ mBw,
    unsigned short* __restrict__ memB,
    float* __restrict__ op)
{
  __shared__ __align__(16) unsigned short sIn[26112];  // 3 x 136 slots x 64ci
  const int b = blockIdx.x, by = blockIdx.y, z = blockIdx.z, tid = threadIdx.x;

  const unsigned short* p0 = in0 + (long)b * in0bs;
  const unsigned short* p1 = hB + ((long)b << 16);
  const unsigned short* p2 = mBr + ((long)b << 16);
  for (int s = tid; s < 1088; s += 128) stage64(p0, sIn, s, by);
  for (int s = tid; s < 1088; s += 128) stage64(p1, sIn + 8704, s, by);
  for (int s = tid; s < 1088; s += 128) stage64(p2, sIn + 17408, s, by);
  __syncthreads();

  const int w = tid >> 6, lane = tid & 63, q = lane >> 4, n16 = lane & 15;
  const int g = z * 2 + w;
  const unsigned short* wA = wfAl + (long)g * 129024;
  f32x4 acc[7][4];
  #pragma unroll
  for (int s = 0; s < 7; ++s)
    #pragma unroll
    for (int j = 0; j < 4; ++j) acc[s][j] = (f32x4){0.f, 0.f, 0.f, 0.f};

  conv_section<7, 0, 0>  (sIn,         wA, lane, q, n16, acc);   // x -> all 7
  conv_section<4, 0, 126>(sIn + 8704,  wA, lane, q, n16, acc);   // h -> i,f,g,o
  conv_section<3, 4, 198>(sIn + 17408, wA, lane, q, n16, acc);   // m -> i',f',g'
  __syncthreads();   // all waves done reading sIn before sT overwrite

  unsigned short* sT = sIn;    // 64px x 64ch (32 c | 32 m), swizzled
  const int pxr = by * 64;
  #pragma unroll
  for (int r = 0; r < 4; ++r) {
    const int co = g * 16 + q * 4 + r;
    const float bi  = bAl[co],       bf_ = bAl[64 + co],  bg  = bAl[128 + co];
    const float bo_ = bAl[192 + co], bi2 = bAl[256 + co], bf2 = bAl[320 + co];
    const float bg2 = bAl[384 + co];
    #pragma unroll
    for (int pf = 0; pf < 4; ++pf) {
      const int pxl = (pf >> 1) * 32 + (pf & 1) * 16 + n16;
      const long cmo = ((long)b * 64 + co) * 1024 + pxr + pxl;
      float cn = sigf(acc[1][pf][r] + bf_) * C[cmo] +
                 sigf(acc[0][pf][r] + bi)  * tanhfast(acc[2][pf][r] + bg);
      float mn = sigf(acc[5][pf][r] + bf2) * M[cmo] +
                 sigf(acc[4][pf][r] + bi2) * tanhfast(acc[6][pf][r] + bg2);
      C[cmo] = cn; M[cmo] = mn;
      op[cmo] = acc[3][pf][r] + bo_;
      const int chc = co & 31;
      sT[pxl * 64 + (((chc >> 3) ^ (pxl & 7)) * 8) + (chc & 7)] = f2b(cn);
      const int chm = 32 + chc;
      sT[pxl * 64 + (((chm >> 3) ^ (pxl & 7)) * 8) + (chm & 7)] = f2b(mn);
    }
  }
  __syncthreads();

  for (int k = 0; k < 4; ++k) {
    const int u = tid + k * 128;               // 512 tasks: 64px x 8 ch-vecs
    const int pxl = u >> 3, chv = u & 7;
    uint4 v = *(const uint4*)(sT + pxl * 64 + ((chv ^ (pxl & 7)) * 8));
    const long pxg = (long)b * 1024 + pxr + pxl;
    const int chg = (chv < 4) ? (z * 32 + chv * 8) : (64 + z * 32 + (chv - 4) * 8);
    *(uint4*)(memB + pxg * 128 + chg) = v;
    if (chv >= 4) *(uint4*)(mBw + pxg * 64 + z * 32 + (chv - 4) * 8) = v;
  }
}

// ---------------------------------------------------------------------------
// kcellB: grid (8, 32 rows), 64 threads (1 wave): 64co x 32px, O + L accs.
// ---------------------------------------------------------------------------
__global__ __launch_bounds__(64) void kcellB(
    const unsigned short* __restrict__ memB,
    const unsigned short* __restrict__ wfBl,
    const float* __restrict__ op, const float* __restrict__ bl,
    unsigned short* __restrict__ hBw, unsigned short* __restrict__ outsBt,
    int writeOuts)
{
  __shared__ __align__(16) unsigned short sIn[13056];  // 102 slots x 128ci
  const int b = blockIdx.x, r0 = blockIdx.y, tid = threadIdx.x;
  const unsigned short* bp = memB + ((long)b << 17);
  for (int s = tid; s < 1632; s += 64) {
    int slot = s >> 4, cg = s & 15;
    int rr = slot / 34, cl = slot - rr * 34;
    int gr = r0 - 1 + rr, gc = cl - 1;
    uint4 v = make_uint4(0u, 0u, 0u, 0u);
    if ((unsigned)gr < 32u && (unsigned)gc < 32u)
      v = *(const uint4*)(bp + ((long)(gr * 32 + gc) << 7) + cg * 8);
    *(uint4*)(sIn + slot * 128 + ((cg ^ (slot & 7)) * 8)) = v;
  }
  __syncthreads();

  const int lane = tid, q = lane >> 4, n16 = lane & 15;
  f32x4 accO[4][2], accL[4][2];
  #pragma unroll
  for (int f = 0; f < 4; ++f) {
    accO[f][0] = (f32x4){0.f,0.f,0.f,0.f}; accO[f][1] = (f32x4){0.f,0.f,0.f,0.f};
    accL[f][0] = (f32x4){0.f,0.f,0.f,0.f}; accL[f][1] = (f32x4){0.f,0.f,0.f,0.f};
  }

  #pragma unroll
  for (int cc = 0; cc < 4; ++cc) {
    const int cs = cc * 4 + q;
    #pragma unroll
    for (int dx = 0; dx < 3; ++dx) {
      bf16x8 AO[3][4];
      #pragma unroll
      for (int dy = 0; dy < 3; ++dy)
        #pragma unroll
        for (int f = 0; f < 4; ++f)
          AO[dy][f] = *(const bf16x8*)(wfBl +
              (long)((((cc * 3 + dx) * 3 + dy) * 4) + f) * 512 + lane * 8);
      #pragma unroll
      for (int cg = 0; cg < 2; ++cg) {
        bf16x8 B[3];
        #pragma unroll
        for (int dy = 0; dy < 3; ++dy) {
          const int slot = dy * 34 + cg * 16 + dx + n16;
          B[dy] = *(const bf16x8*)(sIn + slot * 128 + ((cs ^ (slot & 7)) * 8));
        }
        #pragma unroll
        for (int dy = 0; dy < 3; ++dy)
          #pragma unroll
          for (int f = 0; f < 4; ++f)
            accO[f][cg] = mfma16(AO[dy][f], B[dy], accO[f][cg]);
      }
    }
    // convL (center tap only)
    bf16x8 AL[4];
    #pragma unroll
    for (int f = 0; f < 4; ++f)
      AL[f] = *(const bf16x8*)(wfBl + (long)(144 + cc * 4 + f) * 512 + lane * 8);
    #pragma unroll
    for (int cg = 0; cg < 2; ++cg) {
      const int slot = 34 + cg * 16 + 1 + n16;
      bf16x8 Bc = *(const bf16x8*)(sIn + slot * 128 + ((cs ^ (slot & 7)) * 8));
      #pragma unroll
      for (int f = 0; f < 4; ++f)
        accL[f][cg] = mfma16(AL[f], Bc, accL[f][cg]);
    }
  }
  __syncthreads();

  unsigned short* sT = sIn;    // 32px x 64ch swizzled
  #pragma unroll
  for (int pf = 0; pf < 2; ++pf) {
    const int pxl = pf * 16 + n16;
    const int pxg = r0 * 32 + pxl;
    #pragma unroll
    for (int f = 0; f < 4; ++f)
      #pragma unroll
      for (int r = 0; r < 4; ++r) {
        const int co = f * 16 + q * 4 + r;
        float o = accO[f][pf][r] + op[((long)b * 64 + co) * 1024 + pxg];
        float l = accL[f][pf][r] + bl[co];
        sT[pxl * 64 + (((co >> 3) ^ (pxl & 7)) * 8) + (co & 7)] =
            f2b(sigf(o) * tanhfast(l));
      }
  }
  __syncthreads();
  for (int k = 0; k < 4; ++k) {
    const int u = tid + k * 64;                // 256 tasks: 32px x 8 ch-vecs
    const int pxl = u >> 3, chv = u & 7;
    uint4 v = *(const uint4*)(sT + pxl * 64 + ((chv ^ (pxl & 7)) * 8));
    const long pxg = (long)b * 1024 + r0 * 32 + pxl;
    *(uint4*)(hBw + pxg * 64 + chv * 8) = v;
    if (writeOuts) *(uint4*)(outsBt + pxg * 64 + chv * 8) = v;
  }
}

// ---------------------------------------------------------------------------
// Final conv machinery (verbatim from R2/R3, proven correct)
// ---------------------------------------------------------------------------
__device__ __forceinline__ void conv3_acc(
    const unsigned short* __restrict__ ip, int ciStride, int ciOff,
    const unsigned short* __restrict__ wf, int ncc, int ccoff,
    unsigned short* sIn, f32x4 (&acc)[4][4])
{
  const int tid = threadIdx.x;
  const int r0  = (int)blockIdx.y * 8;
  for (int s = tid; s < 2720; s += 256) {
    int slot = s >> 3, cg = s & 7;
    int rr = slot / 34, cl = slot - rr * 34;
    int gr = r0 - 1 + rr, gc = cl - 1;
    uint4 v = make_uint4(0u, 0u, 0u, 0u);
    if ((unsigned)gr < 32u && (unsigned)gc < 32u)
      v = *(const uint4*)(ip + (long)(gr * 32 + gc) * ciStride + ciOff + cg * 8);
    *(uint4*)(sIn + slot * 64 + ((cg ^ (slot & 7)) * 8)) = v;
  }
  __syncthreads();
  const int lane = tid & 63, w = tid >> 6;
  const int q = lane >> 4, n16 = lane & 15;
  #pragma unroll
  for (int i = 0; i < 4; ++i)
    #pragma unroll
    for (int j = 0; j < 4; ++j)
      acc[i][j] = (f32x4){0.f, 0.f, 0.f, 0.f};
  #pragma unroll
  for (int tap = 0; tap < 9; ++tap) {
    const int dy = tap / 3, dx = tap - dy * 3;
    #pragma unroll
    for (int cc = 0; cc < 2; ++cc) {
      const unsigned short* wp = wf + (long)(tap * ncc + ccoff + cc) * 2048 + lane * 8;
      bf16x8 a0 = *(const bf16x8*)(wp);
      bf16x8 a1 = *(const bf16x8*)(wp + 512);
      bf16x8 a2 = *(const bf16x8*)(wp + 1024);
      bf16x8 a3 = *(const bf16x8*)(wp + 1536);
      const int cs = cc * 4 + q;
      bf16x8 bfr[4];
      #pragma unroll
      for (int pf = 0; pf < 4; ++pf) {
        int slot = (w * 2 + (pf >> 1) + dy) * 34 + (pf & 1) * 16 + dx + n16;
        bfr[pf] = *(const bf16x8*)(sIn + slot * 64 + ((cs ^ (slot & 7)) * 8));
      }
      #pragma unroll
      for (int j = 0; j < 4; ++j) {
        acc[0][j] = mfma16(a0, bfr[j], acc[0][j]);
        acc[1][j] = mfma16(a1, bfr[j], acc[1][j]);
        acc[2][j] = mfma16(a2, bfr[j], acc[2][j]);
        acc[3][j] = mfma16(a3, bfr[j], acc[3][j]);
      }
    }
  }
}

__global__ __launch_bounds__(256) void kconv_final(
    const unsigned short* __restrict__ outsB,
    const unsigned short* __restrict__ wdf, const float* __restrict__ bd,
    float* __restrict__ dout)
{
  __shared__ __align__(16) unsigned short sIn[21760];
  const int img = blockIdx.x;
  const int b = img / 19, t = img - b * 19;
  f32x4 acc[4][4];
  conv3_acc(outsB + ((long)t * 8 + b) * 65536, 64, 0, wdf, 2, 0, sIn, acc);
  const int tid = threadIdx.x;
  const int lane = tid & 63, w = tid >> 6;
  const int q = lane >> 4, n16 = lane & 15;
  const int r0 = (int)blockIdx.y * 8;
  float* ob = dout + (long)img * 65536;
  #pragma unroll
  for (int i = 0; i < 4; ++i) {
    #pragma unroll
    for (int r = 0; r < 4; ++r) {
      const int co = i * 16 + q * 4 + r;
      const float bv = bd[co];
      #pragma unroll
      for (int j = 0; j < 4; ++j) {
        int row = r0 + w * 2 + (j >> 1);
        int col = (j & 1) * 16 + n16;
        ob[((co >> 3) * 32 + row) * 256 + (co & 7) * 32 + col] = sigf(acc[i][j][r] + bv);
      }
    }
  }
}

// patch division -> bf16 channels-last [b*10+t][1024][64]; grid (80)
__global__ __launch_bounds__(256) void kpatch(const float* __restrict__ x,
                                              unsigned short* __restrict__ xpB)
{
  __shared__ __align__(16) unsigned short sT[2048];
  const int img = blockIdx.x, tid = threadIdx.x;
  const float* xi = x + (long)img * 65536;
  unsigned short* xo = xpB + (long)img * 65536;
  for (int p = 0; p < 32; ++p) {
    __syncthreads();
    int ch = tid >> 2, q0 = (tid & 3) * 8;
    const float* s = xi + ((ch >> 3) * 32 + p) * 256 + (ch & 7) * 32 + q0;
    float4 v0 = *(const float4*)s, v1 = *(const float4*)(s + 4);
    float vv[8] = {v0.x, v0.y, v0.z, v0.w, v1.x, v1.y, v1.z, v1.w};
    #pragma unroll
    for (int k = 0; k < 8; ++k) {
      int qq = q0 + k;
      sT[qq * 64 + (((ch >> 3) ^ (qq & 7)) * 8) + (ch & 7)] = f2b(vv[k]);
    }
    __syncthreads();
    int q = tid >> 3, cg = tid & 7;
    uint4 v = *(const uint4*)(sT + q * 64 + ((cg ^ (q & 7)) * 8));
    *(uint4*)(xo + (long)(p * 32 + q) * 64 + cg * 8) = v;
  }
}

// R2 weight fragment packer (used for Wd only)
__global__ __launch_bounds__(256) void kprepw(const float* __restrict__ src,
                                              unsigned short* __restrict__ dst,
                                              int Cout, int Cin, int KK)
{
  long n = (long)Cout * Cin * KK;
  long idx = (long)blockIdx.x * 256 + threadIdx.x;
  if (idx >= n) return;
  int ncc = Cin >> 5;
  long tmp = idx >> 3; int e = (int)(idx & 7);
  int lane = (int)(tmp & 63); tmp >>= 6;
  int cf = (int)(tmp & 3); tmp >>= 2;
  int cc = (int)(tmp % ncc); tmp /= ncc;
  int tap = (int)(tmp % KK); int chunk = (int)(tmp / KK);
  int co = chunk * 64 + cf * 16 + (lane & 15);
  int ci = cc * 32 + (lane >> 4) * 8 + e;
  dst[idx] = f2b(src[((long)co * Cin + ci) * KK + tap]);
}

// pack stage-1 weights in kcellA consumption order:
// [l][g][frag 0..251][lane][8]; frag: x:(cc,dx)*21+dy*7+s | h:126+.. | m:198+..
__global__ __launch_bounds__(256) void kpackA2(
    const float* __restrict__ Wx, const float* __restrict__ Wh,
    const float* __restrict__ Wm, unsigned short* __restrict__ wfA)
{
  long idx = (long)blockIdx.x * 256 + threadIdx.x;
  if (idx >= 2064384) return;
  int e = (int)(idx & 7);
  int lane = (int)((idx >> 3) & 63);
  long f9 = idx >> 9;
  int frag = (int)(f9 % 252);
  int g    = (int)((f9 / 252) & 3);
  int l    = (int)(f9 / 1008);
  int p, step, dy, s;
  if (frag < 126)      { p = 0; step = frag / 21; int r2 = frag % 21; dy = r2 / 7; s = r2 % 7; }
  else if (frag < 198) { p = 1; int f2 = frag - 126; step = f2 / 12; int r2 = f2 % 12; dy = r2 / 4; s = r2 % 4; }
  else                 { p = 2; int f3 = frag - 198; step = f3 / 9;  int r2 = f3 % 9;  dy = r2 / 3; s = 4 + r2 % 3; }
  int cc = step / 3, dx = step % 3, tap = dy * 3 + dx;
  int ci = cc * 32 + (lane >> 4) * 8 + e;
  int co16 = g * 16 + (lane & 15);
  float v;
  if (p == 0) {
    int rb = (s == 0) ? 0 : (s == 1) ? 64 : (s == 2) ? 128 : (s == 3) ? 384
           : (s == 4) ? 192 : (s == 5) ? 256 : 320;
    v = Wx[((long)(l * 448 + rb + co16)) * 576 + ci * 9 + tap];
  } else if (p == 1) {
    v = Wh[((long)(l * 256 + s * 64 + co16)) * 576 + ci * 9 + tap];
  } else {
    v = Wm[((long)(l * 192 + (s - 4) * 64 + co16)) * 576 + ci * 9 + tap];
  }
  wfA[idx] = f2b(v);
}

// pack convO/convL weights in kcellB order: O: ((cc*3+dx)*3+dy)*4+f ; L: 144+cc*4+f
__global__ __launch_bounds__(256) void kpackB2(
    const float* __restrict__ Wo, const float* __restrict__ Wl,
    unsigned short* __restrict__ wfB)
{
  long idx = (long)blockIdx.x * 256 + threadIdx.x;
  if (idx >= 327680) return;
  int e = (int)(idx & 7);
  int lane = (int)((idx >> 3) & 63);
  long f9 = idx >> 9;
  int frag = (int)(f9 % 160);
  int l    = (int)(f9 / 160);
  float v;
  if (frag < 144) {
    int t2 = frag >> 2, f = frag & 3;
    int dy = t2 % 3, sd = t2 / 3;
    int dx = sd % 3, cc = sd / 3;
    int co = f * 16 + (lane & 15);
    int ci = cc * 32 + (lane >> 4) * 8 + e;
    v = Wo[((long)(l * 64 + co)) * 1152 + ci * 9 + dy * 3 + dx];
  } else {
    int f2 = frag - 144;
    int cc = f2 >> 2, f = f2 & 3;
    int co = f * 16 + (lane & 15);
    int ci = cc * 32 + (lane >> 4) * 8 + e;
    v = Wl[((long)(l * 64 + co)) * 128 + ci];
  }
  wfB[idx] = f2b(v);
}

// pre-summed gate biases: [l][slot i,f,g,o(+bo),i2,f2,g2][64]
__global__ __launch_bounds__(256) void kpackbA(
    const float* __restrict__ bx, const float* __restrict__ bh,
    const float* __restrict__ bm, const float* __restrict__ bo,
    float* __restrict__ bA)
{
  int idx = blockIdx.x * 256 + threadIdx.x;
  if (idx >= 1792) return;
  int ch = idx & 63, w = (idx >> 6) % 7, l = (idx >> 6) / 7;
  const float* bxl = bx + l * 448;
  const float* bhl = bh + l * 256;
  const float* bml = bm + l * 192;
  const float* bol = bo + l * 64;
  float v;
  if (w < 3)       v = bxl[w * 64 + ch] + bhl[w * 64 + ch];
  else if (w == 3) v = bxl[384 + ch] + bhl[192 + ch] + bol[ch];
  else             v = bxl[192 + (w - 4) * 64 + ch] + bml[(w - 4) * 64 + ch];
  bA[idx] = v;
}

extern "C" void kernel_launch(void* const* d_in, const int* in_sizes, int n_in,
                              void* d_out, int out_size, void* d_ws, size_t ws_size,
                              hipStream_t stream)
{
  (void)in_sizes; (void)n_in; (void)out_size;
  if (ws_size < WS_NEEDED_FLOATS * sizeof(float)) return;

  const float* x  = (const float*)d_in[0];
  const float* Wx = (const float*)d_in[3];
  const float* bx = (const float*)d_in[4];
  const float* Wh = (const float*)d_in[5];
  const float* bh = (const float*)d_in[6];
  const float* Wm = (const float*)d_in[7];
  const float* bm = (const float*)d_in[8];
  const float* Wo = (const float*)d_in[9];
  const float* bo = (const float*)d_in[10];
  const float* Wl = (const float*)d_in[11];
  const float* bl = (const float*)d_in[12];
  const float* Wd = (const float*)d_in[13];
  const float* bd = (const float*)d_in[14];
  float* ws  = (float*)d_ws;
  float* out = (float*)d_out;

  unsigned short* xpB   = (unsigned short*)(ws + OFF_XPB);
  unsigned short* outsB = (unsigned short*)(ws + OFF_OUTSB);
  unsigned short* hB    = (unsigned short*)(ws + OFF_HB);
  unsigned short* mB0   = (unsigned short*)(ws + OFF_MB);
  unsigned short* mB1   = mB0 + 524288;
  float*          C     = ws + OFF_C;
  float*          M     = ws + OFF_M;
  unsigned short* memB  = (unsigned short*)(ws + OFF_MEMB);
  float*          OP    = ws + OFF_OP;
  unsigned short* wfA   = (unsigned short*)(ws + OFF_WFA);
  unsigned short* wfB   = (unsigned short*)(ws + OFF_WFB);
  unsigned short* wfD   = (unsigned short*)(ws + OFF_WFD);
  float*          bA    = ws + OFF_BA;

  kpackA2<<<dim3(8064), 256, 0, stream>>>(Wx, Wh, Wm, wfA);
  kpackB2<<<dim3(1280), 256, 0, stream>>>(Wo, Wl, wfB);
  kpackbA<<<dim3(7), 256, 0, stream>>>(bx, bh, bm, bo, bA);
  kprepw<<<dim3(144), 256, 0, stream>>>(Wd, wfD, 64, 64, 9);
  kpatch<<<dim3(80), 256, 0, stream>>>(x, xpB);
  // zero h, m(bf16 x2), C, M (contiguous region)
  hipMemsetAsync(ws + OFF_HB, 0, (OFF_MEMB - OFF_HB) * sizeof(float), stream);

  for (int t = 0; t < T; ++t) {
    for (int l = 0; l < 4; ++l) {
      const int cell = t * 4 + l;
      const unsigned short* in0; long ibs;
      if (l == 0) {
        if (t < INLEN) { in0 = xpB + (long)t * 65536; ibs = 655360; }
        else           { in0 = outsB + (long)(t - 1) * 524288; ibs = 65536; }
      } else {
        in0 = hB + (long)(l - 1) * 524288; ibs = 65536;
      }
      const unsigned short* mBr = (cell & 1) ? mB1 : mB0;
      unsigned short*       mBw = (cell & 1) ? mB0 : mB1;
      kcellA<<<dim3(8, 16, 2), 128, 0, stream>>>(
          in0, ibs, hB + (long)l * 524288, mBr,
          wfA + (long)l * 516096, bA + l * 448,
          C + (long)l * 524288, M, mBw, memB, OP);
      kcellB<<<dim3(8, 32), 64, 0, stream>>>(
          memB, wfB + (long)l * 81920, OP, bl + l * 64,
          hB + (long)l * 524288, outsB + (long)t * 524288, (l == 3) ? 1 : 0);
    }
  }
  kconv_final<<<dim3(152, 4), 256, 0, stream>>>(outsB, wfD, bd, out);
}